// Round 5
// baseline (684.231 us; speedup 1.0000x reference)
//
#include <hip/hip_runtime.h>
#include <math.h>

// Problem constants (from reference)
constexpr int N = 50000, E = 800000, F = 512, P = 128, G = 256, H = 256, T = 24;
// Capacity caps (expected: ~16 edges->target, ~290 2-hop edges, ~300 nodes)
constexpr int CAPA = 4096, CAPB = 32768, CAPP = 2048, CAPH = 512;

// Workspace layout (bytes), 64-aligned
constexpr size_t OFF_DEG   = 0;        // float[N]
constexpr size_t OFF_CNT   = 200704;   // int[16]: 0=cntA,1=cntB,2=cntP,3=cntH
constexpr size_t OFF_FH1   = 200768;   // uchar[N]
constexpr size_t OFF_FP    = 250880;   // uchar[N]
constexpr size_t ZERO_END  = 301056;   // memset [0, ZERO_END)
constexpr size_t OFF_IDXP  = 301056;   // int[N]
constexpr size_t OFF_IDXH1 = 501120;   // int[N]
constexpr size_t OFF_SRCA  = 701184;   // int[CAPA]
constexpr size_t OFF_WA    = 717568;   // float[CAPA]
constexpr size_t OFF_SRCB  = 733952;   // int[CAPB]
constexpr size_t OFF_DSTB  = 865024;   // int[CAPB]
constexpr size_t OFF_WB    = 996096;   // float[CAPB] (pre-normalized by src degree)
constexpr size_t OFF_LISTP = 1127168;  // int[CAPP]
constexpr size_t OFF_LISTH = 1135360;  // int[CAPH]
constexpr size_t OFF_Q     = 1137408;  // float[CAPP*G]
constexpr size_t OFF_RS    = 3234560;  // float[CAPH*G]
constexpr size_t OFF_EMB   = 3758848;  // float[2G] (only [0:256] used now)
constexpr size_t OFF_XPROJ = 3760896;  // float[T*4H]

__device__ __forceinline__ float sigmoidf_(float x) { return 1.0f / (1.0f + expf(-x)); }

// Pass 1: degree accumulation + collect edges whose dst == target; flag 1-hop srcs.
__global__ void k_deg_scan(const int* __restrict__ ei, const float* __restrict__ eg,
                           const int* __restrict__ ptgt, float* __restrict__ deg,
                           int* __restrict__ cnt, unsigned char* __restrict__ fH1,
                           int* __restrict__ srcA, float* __restrict__ wA) {
    int target = *ptgt;
    int e = blockIdx.x * 256 + threadIdx.x;
    if (e < E) {
        int d = ei[E + e];
        float w = eg[e];
        atomicAdd(&deg[d], w);
        if (d == target) {
            int s = ei[e];
            int slot = atomicAdd(&cnt[0], 1);
            if (slot < CAPA) { srcA[slot] = s; wA[slot] = w; }
            fH1[s] = 1;
        }
    }
    if (blockIdx.x == 0 && threadIdx.x == 0) fH1[target] = 1;
}

// Pass 2: collect edges whose dst is a needed-h1 node (weights pre-normalized by
// src degree: wB = w * rsqrt(deg[src]+1)); flag srcs as needing p/q.
__global__ void k_scan2(const int* __restrict__ ei, const float* __restrict__ eg,
                        const float* __restrict__ deg,
                        const unsigned char* __restrict__ fH1, unsigned char* __restrict__ fP,
                        int* __restrict__ cnt, int* __restrict__ srcB,
                        int* __restrict__ dstB, float* __restrict__ wB) {
    int e = blockIdx.x * 256 + threadIdx.x;
    if (e >= E) return;
    int d = ei[E + e];
    if (fH1[d]) {
        int s = ei[e];
        float w = eg[e];
        int slot = atomicAdd(&cnt[1], 1);
        if (slot < CAPB) {
            srcB[slot] = s; dstB[slot] = d;
            wB[slot] = w * rsqrtf(deg[s] + 1.0f);
        }
        fP[s] = 1;
    }
}

// Compact flagged node sets into lists with index maps.
__global__ void k_compact(const unsigned char* __restrict__ fH1, const unsigned char* __restrict__ fP,
                          int* __restrict__ cnt, int* __restrict__ listP, int* __restrict__ listH,
                          int* __restrict__ idxP, int* __restrict__ idxH1) {
    int n = blockIdx.x * 256 + threadIdx.x;
    if (n >= N) return;
    if (fH1[n]) {
        int sh = atomicAdd(&cnt[3], 1);
        if (sh < CAPH) listH[sh] = n;
        idxH1[n] = sh;
    }
    if (fP[n] || fH1[n]) {
        int sp = atomicAdd(&cnt[2], 1);
        if (sp < CAPP) listP[sp] = n;
        idxP[n] = sp;
    }
}

// q[row] = relu((x[n]*feat_gate) @ W_proj + b_proj) @ W_g1.
// 256 blocks, round-robin rows (all blocks active), deep unroll for MLP.
__global__ void k_pq(const float* __restrict__ x, const float* __restrict__ fgate,
                     const float* __restrict__ Wproj, const float* __restrict__ bproj,
                     const float* __restrict__ Wg1, const int* __restrict__ cnt,
                     const int* __restrict__ listP, float* __restrict__ q) {
    __shared__ float xm[F];
    __shared__ float part[256];
    __shared__ float pv[P];
    int nP = min(cnt[2], CAPP);
    int tid = threadIdx.x;  // 256
    for (int row = blockIdx.x; row < nP; row += 256) {
        int n = listP[row];
        __syncthreads();  // protect LDS reuse across row iterations
        for (int i = tid; i < F; i += 256) xm[i] = x[(size_t)n * F + i] * fgate[i];
        __syncthreads();
        // stage 1: thread = (col 0..127, k-half 0..1), 256 k each
        int col = tid & 127, kh = tid >> 7;
        const float* wp = Wproj + (size_t)(kh * 256) * P + col;
        const float* xh = xm + kh * 256;
        float acc = 0.0f;
        #pragma unroll 16
        for (int k = 0; k < 256; k++) acc += xh[k] * wp[(size_t)k * P];
        part[tid] = acc;
        __syncthreads();
        if (tid < P) pv[tid] = fmaxf(part[tid] + part[tid + 128] + bproj[tid], 0.0f);
        __syncthreads();
        // stage 2: col = tid over G
        float a = 0.0f;
        #pragma unroll 16
        for (int k = 0; k < P; k++) a += pv[k] * Wg1[k * G + tid];
        q[(size_t)row * G + tid] = a;
    }
}

// h1 for 1-hop-set nodes, then r = h1 @ W_g2. Edge list staged through LDS.
// Also capture h1[target] -> emb[0:256].
__global__ void k_h1(const int* __restrict__ ptgt, const float* __restrict__ deg,
                     const int* __restrict__ cnt, const int* __restrict__ listH,
                     const int* __restrict__ idxP, const int* __restrict__ srcB,
                     const int* __restrict__ dstB, const float* __restrict__ wB,
                     const float* __restrict__ q, const float* __restrict__ bg1,
                     const float* __restrict__ Wg2,
                     float* __restrict__ rs, float* __restrict__ emb) {
    __shared__ float h1row[G];
    __shared__ int ldst[512];
    __shared__ int lsrc[512];
    __shared__ float lw[512];
    int b = blockIdx.x;
    int nH = min(cnt[3], CAPH);
    if (b >= nH) return;
    int n = listH[b];
    int target = *ptgt;
    int g = threadIdx.x;  // 256 threads
    float dn = rsqrtf(deg[n] + 1.0f);
    float acc = bg1[g] + q[(size_t)idxP[n] * G + g] * dn * dn;
    int nB = min(cnt[1], CAPB);
    for (int base = 0; base < nB; base += 512) {
        int m = min(512, nB - base);
        __syncthreads();
        for (int i = g; i < m; i += 256) {
            ldst[i] = dstB[base + i]; lsrc[i] = srcB[base + i]; lw[i] = wB[base + i];
        }
        __syncthreads();
        for (int e = 0; e < m; e++) {
            if (ldst[e] == n)
                acc += lw[e] * dn * q[(size_t)idxP[lsrc[e]] * G + g];
        }
    }
    float hv = fmaxf(acc, 0.0f);
    h1row[g] = hv;
    if (n == target) emb[g] = hv;
    __syncthreads();
    float r = 0.0f;
    #pragma unroll 8
    for (int k = 0; k < G; k++) r += h1row[k] * Wg2[k * G + g];
    rs[(size_t)b * G + g] = r;
}

// xproj[t][j] = seq[t] @ W_ih[:,j] + b_ih[j] + b_hh[j]; seq built in-LDS from
// cached + emb (h1 target) + h2 target (recomputed redundantly per block).
// 32 blocks x 256 threads; block owns 32 columns, all T rows.
__global__ void k_xproj(const float* __restrict__ cached, const float* __restrict__ emb,
                        const int* __restrict__ ptgt, const int* __restrict__ pepos,
                        const float* __restrict__ deg, const int* __restrict__ cnt,
                        const int* __restrict__ idxH1, const int* __restrict__ srcA,
                        const float* __restrict__ wA, const float* __restrict__ rs,
                        const float* __restrict__ bg2,
                        const float* __restrict__ Wih, const float* __restrict__ bih,
                        const float* __restrict__ bhh, float* __restrict__ xproj) {
    __shared__ float s[T][2 * G];  // 48 KB
    int tid = threadIdx.x;
    int epos = *pepos;
    // stage cached + emb (epos row second half patched after h2 compute)
    for (int i = tid; i < T * 2 * G; i += 256) {
        int t = i >> 9, k = i & 511;
        s[t][k] = (t == epos && k < G) ? emb[k] : cached[i];
    }
    // h2[target] (redundant per block, ~16 edges)
    int target = *ptgt;
    float dt = rsqrtf(deg[target] + 1.0f);
    float h2v = 0.0f;
    if (tid < G) {
        int it = idxH1[target];
        h2v = bg2[tid] + rs[(size_t)it * G + tid] * dt * dt;
        int nA = min(cnt[0], CAPA);
        for (int e = 0; e < nA; e++) {
            int sn = srcA[e];
            h2v += rsqrtf(deg[sn] + 1.0f) * wA[e] * dt * rs[(size_t)idxH1[sn] * G + tid];
        }
    }
    __syncthreads();
    if (tid < G) s[epos][G + tid] = fmaxf(h2v, 0.0f);
    __syncthreads();
    int col = blockIdx.x * 32 + (tid & 31);
    int tg = tid >> 5;  // 0..7
    float base = bih[col] + bhh[col];
    float acc[3];
    #pragma unroll
    for (int i = 0; i < 3; i++) acc[i] = base;
    #pragma unroll 16
    for (int k = 0; k < 2 * G; k++) {
        float wv = Wih[k * 4 * H + col];
        #pragma unroll
        for (int i = 0; i < 3; i++) acc[i] += s[tg + i * 8][k] * wv;
    }
    #pragma unroll
    for (int i = 0; i < 3; i++) xproj[(tg + i * 8) * 4 * H + col] = acc[i];
}

// LSTM in a SINGLE workgroup: 1024 threads (16 waves), thread owns gate column
// tid. Its 256-element W_hh column lives in 16 named ext_vector(16) variables —
// first-class SSA values, NO alloca, so they MUST be register-allocated
// (rule #20: arrays -> scratch; R4's VGPR_Count=64 proved the spill).
// h exchange via LDS + __syncthreads (no cross-WG sync). Tail fused.
typedef float fv16 __attribute__((ext_vector_type(16)));

#define LDE(J,Eidx) wv##J[Eidx] = Whh[(size_t)((J) * 16 + (Eidx)) * 1024 + tid];
#define LDV(J) LDE(J,0) LDE(J,1) LDE(J,2) LDE(J,3) LDE(J,4) LDE(J,5) LDE(J,6) LDE(J,7) \
               LDE(J,8) LDE(J,9) LDE(J,10) LDE(J,11) LDE(J,12) LDE(J,13) LDE(J,14) LDE(J,15)

#define DOT4(J,Q,ACC) { float4 h4 = hb4[(J) * 4 + (Q)]; \
    ACC += h4.x * wv##J[4*(Q)] + h4.y * wv##J[4*(Q)+1] \
         + h4.z * wv##J[4*(Q)+2] + h4.w * wv##J[4*(Q)+3]; }
#define DOTV(J) DOT4(J,0,a0) DOT4(J,1,a1) DOT4(J,2,a2) DOT4(J,3,a3)

__global__ __launch_bounds__(1024, 4) void k_lstm(
        const float* __restrict__ Whh, const float* __restrict__ xproj,
        const float* __restrict__ Watt, const float* __restrict__ batt,
        const float* __restrict__ Wp1, const float* __restrict__ bp1,
        const float* __restrict__ Wp2, const float* __restrict__ bp2,
        float* __restrict__ out) {
    __shared__ __align__(16) float hbuf[H];   // 1 KB
    __shared__ float glds[4 * H];             // 4 KB
    __shared__ float rnn_lds[T][H];           // 24 KB
    __shared__ float sc[T];
    __shared__ float attw[T];
    __shared__ float ctx_l[H];
    __shared__ float watt_l[H];
    __shared__ float part[1024];
    __shared__ float hid_l[64];
    __shared__ float wp2_l[64];

    int tid = threadIdx.x;

    // Preload this thread's W_hh column into 256 register lanes (coalesced).
    fv16 wv0, wv1, wv2, wv3, wv4, wv5, wv6, wv7;
    fv16 wv8, wv9, wv10, wv11, wv12, wv13, wv14, wv15;
    LDV(0) LDV(1) LDV(2) LDV(3) LDV(4) LDV(5) LDV(6) LDV(7)
    LDV(8) LDV(9) LDV(10) LDV(11) LDV(12) LDV(13) LDV(14) LDV(15)

    const float4* hb4 = (const float4*)hbuf;
    if (tid < H) hbuf[tid] = 0.0f;
    float cstate = 0.0f;               // live in tid < 256
    float xnext = xproj[tid];          // prefetch t=0
    __syncthreads();

    for (int t = 0; t < T; t++) {
        float xt = xnext;
        if (t + 1 < T) xnext = xproj[(t + 1) * 4 * H + tid];  // in flight during matvec
        float a0 = 0.0f, a1 = 0.0f, a2 = 0.0f, a3 = 0.0f;
        DOTV(0) DOTV(1) DOTV(2) DOTV(3) DOTV(4) DOTV(5) DOTV(6) DOTV(7)
        DOTV(8) DOTV(9) DOTV(10) DOTV(11) DOTV(12) DOTV(13) DOTV(14) DOTV(15)
        glds[tid] = ((a0 + a1) + (a2 + a3)) + xt;
        __syncthreads();
        if (tid < H) {
            float gi = glds[tid], gf = glds[H + tid], gg = glds[2 * H + tid], go = glds[3 * H + tid];
            cstate = sigmoidf_(gf) * cstate + sigmoidf_(gi) * tanhf(gg);
            float hv = sigmoidf_(go) * tanhf(cstate);
            hbuf[tid] = hv;
            rnn_lds[t][tid] = hv;
        }
        __syncthreads();
    }

    // ---- attention + MLP tail ----
    if (tid < H) watt_l[tid] = Watt[tid];
    if (tid < 64) wp2_l[tid] = Wp2[tid];
    __syncthreads();
    if (tid < T) {
        float sv = 0.0f;
        #pragma unroll 8
        for (int h = 0; h < H; h++) sv += rnn_lds[tid][h] * watt_l[h];
        sc[tid] = tanhf(sv + batt[0]);
    }
    __syncthreads();
    if (tid == 0) {
        float m = -1e30f;
        for (int t = 0; t < T; t++) m = fmaxf(m, sc[t]);
        float su = 0.0f;
        for (int t = 0; t < T; t++) { float e = expf(sc[t] - m); attw[t] = e; su += e; }
        float inv = 1.0f / su;
        for (int t = 0; t < T; t++) attw[t] *= inv;
    }
    __syncthreads();
    if (tid < H) {
        float a = 0.0f;
        #pragma unroll
        for (int t = 0; t < T; t++) a += rnn_lds[t][tid] * attw[t];
        ctx_l[tid] = a;
    }
    __syncthreads();
    {
        int col = tid & 63, sl = tid >> 6;  // 16 k-slices of 16
        float a = 0.0f;
        #pragma unroll
        for (int kk = 0; kk < 16; kk++) {
            int k = sl * 16 + kk;
            a += ctx_l[k] * Wp1[k * 64 + col];
        }
        part[tid] = a;
    }
    __syncthreads();
    if (tid < 64) {
        float a = bp1[tid];
        #pragma unroll
        for (int s2 = 0; s2 < 16; s2++) a += part[s2 * 64 + tid];
        hid_l[tid] = fmaxf(a, 0.0f);
    }
    __syncthreads();
    if (tid == 0) {
        float r = bp2[0];
        #pragma unroll
        for (int j = 0; j < 64; j++) r += hid_l[j] * wp2_l[j];
        out[0] = (r > 20.0f) ? r : log1pf(expf(r));
    }
}

extern "C" void kernel_launch(void* const* d_in, const int* in_sizes, int n_in,
                              void* d_out, int out_size, void* d_ws, size_t ws_size,
                              hipStream_t stream) {
    const float* x      = (const float*)d_in[0];
    const int*   ei     = (const int*)d_in[1];
    const float* fgate  = (const float*)d_in[2];
    const float* egate  = (const float*)d_in[3];
    const float* cached = (const float*)d_in[4];
    const float* Wproj  = (const float*)d_in[5];
    const float* bproj  = (const float*)d_in[6];
    const float* Wg1    = (const float*)d_in[7];
    const float* bg1    = (const float*)d_in[8];
    const float* Wg2    = (const float*)d_in[9];
    const float* bg2    = (const float*)d_in[10];
    const float* Wih    = (const float*)d_in[11];
    const float* Whh    = (const float*)d_in[12];
    const float* bih    = (const float*)d_in[13];
    const float* bhh    = (const float*)d_in[14];
    const float* Watt   = (const float*)d_in[15];
    const float* batt   = (const float*)d_in[16];
    const float* Wp1    = (const float*)d_in[17];
    const float* bp1    = (const float*)d_in[18];
    const float* Wp2    = (const float*)d_in[19];
    const float* bp2    = (const float*)d_in[20];
    const int*   ptgt   = (const int*)d_in[21];
    const int*   pepos  = (const int*)d_in[22];

    char* ws = (char*)d_ws;
    float* deg   = (float*)(ws + OFF_DEG);
    int*   cnt   = (int*)(ws + OFF_CNT);
    unsigned char* fH1 = (unsigned char*)(ws + OFF_FH1);
    unsigned char* fP  = (unsigned char*)(ws + OFF_FP);
    int*   idxP  = (int*)(ws + OFF_IDXP);
    int*   idxH1 = (int*)(ws + OFF_IDXH1);
    int*   srcA  = (int*)(ws + OFF_SRCA);
    float* wA    = (float*)(ws + OFF_WA);
    int*   srcB  = (int*)(ws + OFF_SRCB);
    int*   dstB  = (int*)(ws + OFF_DSTB);
    float* wB    = (float*)(ws + OFF_WB);
    int*   listP = (int*)(ws + OFF_LISTP);
    int*   listH = (int*)(ws + OFF_LISTH);
    float* q     = (float*)(ws + OFF_Q);
    float* rs    = (float*)(ws + OFF_RS);
    float* emb   = (float*)(ws + OFF_EMB);
    float* xproj = (float*)(ws + OFF_XPROJ);

    hipMemsetAsync(ws, 0, ZERO_END, stream);

    k_deg_scan<<<(E + 255) / 256, 256, 0, stream>>>(ei, egate, ptgt, deg, cnt, fH1, srcA, wA);
    k_scan2<<<(E + 255) / 256, 256, 0, stream>>>(ei, egate, deg, fH1, fP, cnt, srcB, dstB, wB);
    k_compact<<<(N + 255) / 256, 256, 0, stream>>>(fH1, fP, cnt, listP, listH, idxP, idxH1);
    k_pq<<<256, 256, 0, stream>>>(x, fgate, Wproj, bproj, Wg1, cnt, listP, q);
    k_h1<<<CAPH, 256, 0, stream>>>(ptgt, deg, cnt, listH, idxP, srcB, dstB, wB, q, bg1, Wg2, rs, emb);
    k_xproj<<<32, 256, 0, stream>>>(cached, emb, ptgt, pepos, deg, cnt, idxH1, srcA, wA, rs, bg2,
                                    Wih, bih, bhh, xproj);
    k_lstm<<<1, 1024, 0, stream>>>(Whh, xproj, Watt, batt, Wp1, bp1, Wp2, bp2, (float*)d_out);
}

// Round 6
// 206.545 us; speedup vs baseline: 3.3127x; 3.3127x over previous
//
#include <hip/hip_runtime.h>
#include <math.h>

// Problem constants (from reference)
constexpr int N = 50000, E = 800000, F = 512, P = 128, G = 256, H = 256, T = 24;
// Capacity caps (expected: ~16 edges->target, ~290 2-hop edges, ~300 nodes)
constexpr int CAPA = 4096, CAPB = 32768, CAPP = 2048, CAPH = 512;

// Workspace layout (bytes), 64-aligned
constexpr size_t OFF_DEG   = 0;        // float[N]
constexpr size_t OFF_CNT   = 200704;   // int[16]: 0=cntA,1=cntB,2=cntP,3=cntH
constexpr size_t OFF_COMM  = 200768;   // ull[2][256] tagged h-words (ping-pong)
constexpr size_t OFF_FH1   = 204864;   // uchar[N]
constexpr size_t OFF_FP    = 254912;   // uchar[N]
constexpr size_t ZERO_END  = 304960;   // memset [0, ZERO_END)
constexpr size_t OFF_IDXP  = 304960;   // int[N]
constexpr size_t OFF_IDXH1 = 504960;   // int[N]
constexpr size_t OFF_SRCA  = 704960;   // int[CAPA]
constexpr size_t OFF_WA    = 721344;   // float[CAPA]
constexpr size_t OFF_SRCB  = 737728;   // int[CAPB]
constexpr size_t OFF_DSTB  = 868800;   // int[CAPB]
constexpr size_t OFF_WB    = 999872;   // float[CAPB] (pre-normalized by src degree)
constexpr size_t OFF_LISTP = 1130944;  // int[CAPP]
constexpr size_t OFF_LISTH = 1139136;  // int[CAPH]
constexpr size_t OFF_Q     = 1141184;  // float[CAPP*G]
constexpr size_t OFF_RS    = 3238336;  // float[CAPH*G]
constexpr size_t OFF_EMB   = 3762624;  // float[2G] (only [0:256] used)
constexpr size_t OFF_XPROJ = 3764672;  // float[T*4H]

__device__ __forceinline__ float sigmoidf_(float x) { return 1.0f / (1.0f + expf(-x)); }

// Pass 1: degree accumulation + collect edges whose dst == target; flag 1-hop srcs.
__global__ void k_deg_scan(const int* __restrict__ ei, const float* __restrict__ eg,
                           const int* __restrict__ ptgt, float* __restrict__ deg,
                           int* __restrict__ cnt, unsigned char* __restrict__ fH1,
                           int* __restrict__ srcA, float* __restrict__ wA) {
    int target = *ptgt;
    int e = blockIdx.x * 256 + threadIdx.x;
    if (e < E) {
        int d = ei[E + e];
        float w = eg[e];
        atomicAdd(&deg[d], w);
        if (d == target) {
            int s = ei[e];
            int slot = atomicAdd(&cnt[0], 1);
            if (slot < CAPA) { srcA[slot] = s; wA[slot] = w; }
            fH1[s] = 1;
        }
    }
    if (blockIdx.x == 0 && threadIdx.x == 0) fH1[target] = 1;
}

// Pass 2: collect edges whose dst is a needed-h1 node (weights pre-normalized by
// src degree: wB = w * rsqrt(deg[src]+1)); flag srcs as needing p/q.
__global__ void k_scan2(const int* __restrict__ ei, const float* __restrict__ eg,
                        const float* __restrict__ deg,
                        const unsigned char* __restrict__ fH1, unsigned char* __restrict__ fP,
                        int* __restrict__ cnt, int* __restrict__ srcB,
                        int* __restrict__ dstB, float* __restrict__ wB) {
    int e = blockIdx.x * 256 + threadIdx.x;
    if (e >= E) return;
    int d = ei[E + e];
    if (fH1[d]) {
        int s = ei[e];
        float w = eg[e];
        int slot = atomicAdd(&cnt[1], 1);
        if (slot < CAPB) {
            srcB[slot] = s; dstB[slot] = d;
            wB[slot] = w * rsqrtf(deg[s] + 1.0f);
        }
        fP[s] = 1;
    }
}

// Compact flagged node sets into lists with index maps.
__global__ void k_compact(const unsigned char* __restrict__ fH1, const unsigned char* __restrict__ fP,
                          int* __restrict__ cnt, int* __restrict__ listP, int* __restrict__ listH,
                          int* __restrict__ idxP, int* __restrict__ idxH1) {
    int n = blockIdx.x * 256 + threadIdx.x;
    if (n >= N) return;
    if (fH1[n]) {
        int sh = atomicAdd(&cnt[3], 1);
        if (sh < CAPH) listH[sh] = n;
        idxH1[n] = sh;
    }
    if (fP[n] || fH1[n]) {
        int sp = atomicAdd(&cnt[2], 1);
        if (sp < CAPP) listP[sp] = n;
        idxP[n] = sp;
    }
}

// q[row] = relu((x[n]*feat_gate) @ W_proj + b_proj) @ W_g1.
// 256 blocks, round-robin rows (all blocks active), deep unroll.
__global__ void k_pq(const float* __restrict__ x, const float* __restrict__ fgate,
                     const float* __restrict__ Wproj, const float* __restrict__ bproj,
                     const float* __restrict__ Wg1, const int* __restrict__ cnt,
                     const int* __restrict__ listP, float* __restrict__ q) {
    __shared__ float xm[F];
    __shared__ float part[256];
    __shared__ float pv[P];
    int nP = min(cnt[2], CAPP);
    int tid = threadIdx.x;  // 256
    for (int row = blockIdx.x; row < nP; row += 256) {
        int n = listP[row];
        __syncthreads();  // protect LDS reuse across row iterations
        for (int i = tid; i < F; i += 256) xm[i] = x[(size_t)n * F + i] * fgate[i];
        __syncthreads();
        int col = tid & 127, kh = tid >> 7;
        const float* wp = Wproj + (size_t)(kh * 256) * P + col;
        const float* xh = xm + kh * 256;
        float acc = 0.0f;
        #pragma unroll 16
        for (int k = 0; k < 256; k++) acc += xh[k] * wp[(size_t)k * P];
        part[tid] = acc;
        __syncthreads();
        if (tid < P) pv[tid] = fmaxf(part[tid] + part[tid + 128] + bproj[tid], 0.0f);
        __syncthreads();
        float a = 0.0f;
        #pragma unroll 16
        for (int k = 0; k < P; k++) a += pv[k] * Wg1[k * G + tid];
        q[(size_t)row * G + tid] = a;
    }
}

// h1 for 1-hop-set nodes, then r = h1 @ W_g2. Edge list staged through LDS.
// Also capture h1[target] -> emb[0:256].
__global__ void k_h1(const int* __restrict__ ptgt, const float* __restrict__ deg,
                     const int* __restrict__ cnt, const int* __restrict__ listH,
                     const int* __restrict__ idxP, const int* __restrict__ srcB,
                     const int* __restrict__ dstB, const float* __restrict__ wB,
                     const float* __restrict__ q, const float* __restrict__ bg1,
                     const float* __restrict__ Wg2,
                     float* __restrict__ rs, float* __restrict__ emb) {
    __shared__ float h1row[G];
    __shared__ int ldst[512];
    __shared__ int lsrc[512];
    __shared__ float lw[512];
    int b = blockIdx.x;
    int nH = min(cnt[3], CAPH);
    if (b >= nH) return;
    int n = listH[b];
    int target = *ptgt;
    int g = threadIdx.x;  // 256 threads
    float dn = rsqrtf(deg[n] + 1.0f);
    float acc = bg1[g] + q[(size_t)idxP[n] * G + g] * dn * dn;
    int nB = min(cnt[1], CAPB);
    for (int base = 0; base < nB; base += 512) {
        int m = min(512, nB - base);
        __syncthreads();
        for (int i = g; i < m; i += 256) {
            ldst[i] = dstB[base + i]; lsrc[i] = srcB[base + i]; lw[i] = wB[base + i];
        }
        __syncthreads();
        for (int e = 0; e < m; e++) {
            if (ldst[e] == n)
                acc += lw[e] * dn * q[(size_t)idxP[lsrc[e]] * G + g];
        }
    }
    float hv = fmaxf(acc, 0.0f);
    h1row[g] = hv;
    if (n == target) emb[g] = hv;
    __syncthreads();
    float r = 0.0f;
    #pragma unroll 8
    for (int k = 0; k < G; k++) r += h1row[k] * Wg2[k * G + g];
    rs[(size_t)b * G + g] = r;
}

// xproj[t][j] = seq[t] @ W_ih[:,j] + b_ih[j] + b_hh[j]; seq built in-LDS from
// cached + emb (h1 target) + h2 target (recomputed redundantly per block).
// 32 blocks x 256 threads; block owns 32 columns, all T rows.
__global__ void k_xproj(const float* __restrict__ cached, const float* __restrict__ emb,
                        const int* __restrict__ ptgt, const int* __restrict__ pepos,
                        const float* __restrict__ deg, const int* __restrict__ cnt,
                        const int* __restrict__ idxH1, const int* __restrict__ srcA,
                        const float* __restrict__ wA, const float* __restrict__ rs,
                        const float* __restrict__ bg2,
                        const float* __restrict__ Wih, const float* __restrict__ bih,
                        const float* __restrict__ bhh, float* __restrict__ xproj) {
    __shared__ float s[T][2 * G];  // 48 KB
    int tid = threadIdx.x;
    int epos = *pepos;
    for (int i = tid; i < T * 2 * G; i += 256) {
        int t = i >> 9, k = i & 511;
        s[t][k] = (t == epos && k < G) ? emb[k] : cached[i];
    }
    // h2[target] (redundant per block, ~16 edges)
    int target = *ptgt;
    float dt = rsqrtf(deg[target] + 1.0f);
    float h2v = 0.0f;
    if (tid < G) {
        int it = idxH1[target];
        h2v = bg2[tid] + rs[(size_t)it * G + tid] * dt * dt;
        int nA = min(cnt[0], CAPA);
        for (int e = 0; e < nA; e++) {
            int sn = srcA[e];
            h2v += rsqrtf(deg[sn] + 1.0f) * wA[e] * dt * rs[(size_t)idxH1[sn] * G + tid];
        }
    }
    __syncthreads();
    if (tid < G) s[epos][G + tid] = fmaxf(h2v, 0.0f);
    __syncthreads();
    int col = blockIdx.x * 32 + (tid & 31);
    int tg = tid >> 5;  // 0..7
    float base = bih[col] + bhh[col];
    float acc[3];
    #pragma unroll
    for (int i = 0; i < 3; i++) acc[i] = base;
    #pragma unroll 16
    for (int k = 0; k < 2 * G; k++) {
        float wv = Wih[k * 4 * H + col];
        #pragma unroll
        for (int i = 0; i < 3; i++) acc[i] += s[tg + i * 8][k] * wv;
    }
    #pragma unroll
    for (int i = 0; i < 3; i++) xproj[(tg + i * 8) * 4 * H + col] = acc[i];
}

// LSTM over 4 WGs x 256 threads (4 waves/WG = 1 wave/SIMD -> VGPR cap 512).
// WG w owns hidden channels [w*64, w*64+64), all 4 gates: thread (g=tid>>6,
// l=tid&63) owns gate column g*H + w*64 + l, with its full 256-element W_hh
// column in 16 named fv16 register vectors (~300 VGPR, legal at 1 wave/SIMD —
// R5's 1024-thread block capped VGPR at 128 and forced the spill).
// Cross-WG: tagged-word relaxed agent atomics, ping-pong (R3 scheme).
typedef float fv16 __attribute__((ext_vector_type(16)));

#define LDE(J,Eidx) wv##J[Eidx] = Whh[(size_t)((J) * 16 + (Eidx)) * 1024 + col];
#define LDV(J) LDE(J,0) LDE(J,1) LDE(J,2) LDE(J,3) LDE(J,4) LDE(J,5) LDE(J,6) LDE(J,7) \
               LDE(J,8) LDE(J,9) LDE(J,10) LDE(J,11) LDE(J,12) LDE(J,13) LDE(J,14) LDE(J,15)

#define DOT4(J,Q,ACC) { float4 h4 = hb4[(J) * 4 + (Q)]; \
    ACC += h4.x * wv##J[4*(Q)] + h4.y * wv##J[4*(Q)+1] \
         + h4.z * wv##J[4*(Q)+2] + h4.w * wv##J[4*(Q)+3]; }
#define DOTV(J) DOT4(J,0,a0) DOT4(J,1,a1) DOT4(J,2,a2) DOT4(J,3,a3)

__global__ __launch_bounds__(256, 1) void k_lstm(
        const float* __restrict__ Whh, const float* __restrict__ xproj,
        unsigned long long* __restrict__ comm,
        const float* __restrict__ Watt, const float* __restrict__ batt,
        const float* __restrict__ Wp1, const float* __restrict__ bp1,
        const float* __restrict__ Wp2, const float* __restrict__ bp2,
        float* __restrict__ out) {
    __shared__ __align__(16) float hbuf[H];   // 1 KB
    __shared__ float glds[4 * 64];            // gate exchange
    __shared__ float rnn_lds[T][H];           // 24 KB (WG0 tail)
    __shared__ float sc[T];
    __shared__ float attw[T];
    __shared__ float ctx_l[H];
    __shared__ float watt_l[H];
    __shared__ float part[256];
    __shared__ float hid_l[64];
    __shared__ float wp2_l[64];

    int w = blockIdx.x;        // 0..3
    int tid = threadIdx.x;     // 0..255
    int l = tid & 63;          // local channel
    int col = (tid >> 6) * H + w * 64 + l;  // global gate column

    // Preload this thread's W_hh column into 256 register lanes (coalesced).
    fv16 wv0, wv1, wv2, wv3, wv4, wv5, wv6, wv7;
    fv16 wv8, wv9, wv10, wv11, wv12, wv13, wv14, wv15;
    LDV(0) LDV(1) LDV(2) LDV(3) LDV(4) LDV(5) LDV(6) LDV(7)
    LDV(8) LDV(9) LDV(10) LDV(11) LDV(12) LDV(13) LDV(14) LDV(15)

    float xcol[T];
    #pragma unroll
    for (int t = 0; t < T; t++) xcol[t] = xproj[t * 4 * H + col];

    const float4* hb4 = (const float4*)hbuf;
    hbuf[tid] = 0.0f;
    float cstate = 0.0f;   // live in tid < 64
    __syncthreads();

    for (int t = 0; t < T; t++) {
        float a0 = 0.0f, a1 = 0.0f, a2 = 0.0f, a3 = 0.0f;
        DOTV(0) DOTV(1) DOTV(2) DOTV(3) DOTV(4) DOTV(5) DOTV(6) DOTV(7)
        DOTV(8) DOTV(9) DOTV(10) DOTV(11) DOTV(12) DOTV(13) DOTV(14) DOTV(15)
        glds[tid] = ((a0 + a1) + (a2 + a3)) + xcol[t];
        __syncthreads();
        int s = t + 1;
        if (tid < 64) {
            float gi = glds[l], gf = glds[64 + l], gg = glds[128 + l], go = glds[192 + l];
            cstate = sigmoidf_(gf) * cstate + sigmoidf_(gi) * tanhf(gg);
            float hv = sigmoidf_(go) * tanhf(cstate);
            hbuf[w * 64 + l] = hv;  // own channels direct to LDS
            unsigned long long word =
                ((unsigned long long)__float_as_uint(hv) << 32) | (unsigned)s;
            __hip_atomic_store(&comm[(size_t)(s & 1) * 256 + w * 64 + l], word,
                               __ATOMIC_RELAXED, __HIP_MEMORY_SCOPE_AGENT);
        }
        // poll foreign channels: thread tid owns channel tid (channel's WG = tid>>6)
        if ((tid >> 6) != w) {
            const unsigned long long* cb = comm + (size_t)(s & 1) * 256;
            unsigned long long wd;
            do {
                wd = __hip_atomic_load(&cb[tid], __ATOMIC_RELAXED, __HIP_MEMORY_SCOPE_AGENT);
            } while ((unsigned)wd != (unsigned)s);
            hbuf[tid] = __uint_as_float((unsigned)(wd >> 32));
        }
        __syncthreads();
        if (w == 0) rnn_lds[t][tid] = hbuf[tid];
    }

    if (w != 0) return;
    // ---- attention + MLP tail (WG 0 only) ----
    watt_l[tid] = Watt[tid];
    if (tid < 64) wp2_l[tid] = Wp2[tid];
    __syncthreads();
    if (tid < T) {
        float sv = 0.0f;
        #pragma unroll 8
        for (int h = 0; h < H; h++) sv += rnn_lds[tid][h] * watt_l[h];
        sc[tid] = tanhf(sv + batt[0]);
    }
    __syncthreads();
    if (tid == 0) {
        float m = -1e30f;
        for (int t = 0; t < T; t++) m = fmaxf(m, sc[t]);
        float su = 0.0f;
        for (int t = 0; t < T; t++) { float e = expf(sc[t] - m); attw[t] = e; su += e; }
        float inv = 1.0f / su;
        for (int t = 0; t < T; t++) attw[t] *= inv;
    }
    __syncthreads();
    {
        float a = 0.0f;
        #pragma unroll
        for (int t = 0; t < T; t++) a += rnn_lds[t][tid] * attw[t];
        ctx_l[tid] = a;
    }
    __syncthreads();
    {
        int col2 = tid & 63, sl = tid >> 6;  // 4 k-slices of 64
        float a = 0.0f;
        #pragma unroll 16
        for (int kk = 0; kk < 64; kk++) {
            int k = sl * 64 + kk;
            a += ctx_l[k] * Wp1[k * 64 + col2];
        }
        part[tid] = a;
    }
    __syncthreads();
    if (tid < 64) {
        float a = bp1[tid] + part[tid] + part[64 + tid] + part[128 + tid] + part[192 + tid];
        hid_l[tid] = fmaxf(a, 0.0f);
    }
    __syncthreads();
    if (tid == 0) {
        float r = bp2[0];
        #pragma unroll
        for (int j = 0; j < 64; j++) r += hid_l[j] * wp2_l[j];
        out[0] = (r > 20.0f) ? r : log1pf(expf(r));
    }
}

extern "C" void kernel_launch(void* const* d_in, const int* in_sizes, int n_in,
                              void* d_out, int out_size, void* d_ws, size_t ws_size,
                              hipStream_t stream) {
    const float* x      = (const float*)d_in[0];
    const int*   ei     = (const int*)d_in[1];
    const float* fgate  = (const float*)d_in[2];
    const float* egate  = (const float*)d_in[3];
    const float* cached = (const float*)d_in[4];
    const float* Wproj  = (const float*)d_in[5];
    const float* bproj  = (const float*)d_in[6];
    const float* Wg1    = (const float*)d_in[7];
    const float* bg1    = (const float*)d_in[8];
    const float* Wg2    = (const float*)d_in[9];
    const float* bg2    = (const float*)d_in[10];
    const float* Wih    = (const float*)d_in[11];
    const float* Whh    = (const float*)d_in[12];
    const float* bih    = (const float*)d_in[13];
    const float* bhh    = (const float*)d_in[14];
    const float* Watt   = (const float*)d_in[15];
    const float* batt   = (const float*)d_in[16];
    const float* Wp1    = (const float*)d_in[17];
    const float* bp1    = (const float*)d_in[18];
    const float* Wp2    = (const float*)d_in[19];
    const float* bp2    = (const float*)d_in[20];
    const int*   ptgt   = (const int*)d_in[21];
    const int*   pepos  = (const int*)d_in[22];

    char* ws = (char*)d_ws;
    float* deg   = (float*)(ws + OFF_DEG);
    int*   cnt   = (int*)(ws + OFF_CNT);
    unsigned long long* comm = (unsigned long long*)(ws + OFF_COMM);
    unsigned char* fH1 = (unsigned char*)(ws + OFF_FH1);
    unsigned char* fP  = (unsigned char*)(ws + OFF_FP);
    int*   idxP  = (int*)(ws + OFF_IDXP);
    int*   idxH1 = (int*)(ws + OFF_IDXH1);
    int*   srcA  = (int*)(ws + OFF_SRCA);
    float* wA    = (float*)(ws + OFF_WA);
    int*   srcB  = (int*)(ws + OFF_SRCB);
    int*   dstB  = (int*)(ws + OFF_DSTB);
    float* wB    = (float*)(ws + OFF_WB);
    int*   listP = (int*)(ws + OFF_LISTP);
    int*   listH = (int*)(ws + OFF_LISTH);
    float* q     = (float*)(ws + OFF_Q);
    float* rs    = (float*)(ws + OFF_RS);
    float* emb   = (float*)(ws + OFF_EMB);
    float* xproj = (float*)(ws + OFF_XPROJ);

    hipMemsetAsync(ws, 0, ZERO_END, stream);

    k_deg_scan<<<(E + 255) / 256, 256, 0, stream>>>(ei, egate, ptgt, deg, cnt, fH1, srcA, wA);
    k_scan2<<<(E + 255) / 256, 256, 0, stream>>>(ei, egate, deg, fH1, fP, cnt, srcB, dstB, wB);
    k_compact<<<(N + 255) / 256, 256, 0, stream>>>(fH1, fP, cnt, listP, listH, idxP, idxH1);
    k_pq<<<256, 256, 0, stream>>>(x, fgate, Wproj, bproj, Wg1, cnt, listP, q);
    k_h1<<<CAPH, 256, 0, stream>>>(ptgt, deg, cnt, listH, idxP, srcB, dstB, wB, q, bg1, Wg2, rs, emb);
    k_xproj<<<32, 256, 0, stream>>>(cached, emb, ptgt, pepos, deg, cnt, idxH1, srcA, wA, rs, bg2,
                                    Wih, bih, bhh, xproj);
    k_lstm<<<4, 256, 0, stream>>>(Whh, xproj, comm, Watt, batt, Wp1, bp1, Wp2, bp2, (float*)d_out);
}

// Round 7
// 202.034 us; speedup vs baseline: 3.3867x; 1.0223x over previous
//
#include <hip/hip_runtime.h>
#include <math.h>

// Problem constants (from reference)
constexpr int N = 50000, E = 800000, F = 512, P = 128, G = 256, H = 256, T = 24;
// Capacity caps (expected: ~16 edges->target, ~290 2-hop edges, ~300 nodes)
constexpr int CAPA = 4096, CAPB = 32768, CAPP = 2048, CAPH = 512;

// Workspace layout (bytes), 64-aligned
constexpr size_t OFF_DEG   = 0;        // float[N]
constexpr size_t OFF_CNT   = 200704;   // int[16]: 0=cntA,1=cntB,2=cntP,3=cntH,4..11=xcd tickets,12=winner
constexpr size_t OFF_COMM  = 200768;   // ull[2][256] tagged h-words (ping-pong)
constexpr size_t OFF_FH1   = 204864;   // uchar[N]
constexpr size_t OFF_FP    = 254912;   // uchar[N]
constexpr size_t ZERO_END  = 304960;   // memset [0, ZERO_END)
constexpr size_t OFF_IDXP  = 304960;   // int[N]
constexpr size_t OFF_IDXH1 = 504960;   // int[N]
constexpr size_t OFF_SRCA  = 704960;   // int[CAPA]
constexpr size_t OFF_WA    = 721344;   // float[CAPA]
constexpr size_t OFF_SRCB  = 737728;   // int[CAPB]
constexpr size_t OFF_DSTB  = 868800;   // int[CAPB]
constexpr size_t OFF_WB    = 999872;   // float[CAPB] (pre-normalized by src degree)
constexpr size_t OFF_LISTP = 1130944;  // int[CAPP]
constexpr size_t OFF_LISTH = 1139136;  // int[CAPH]
constexpr size_t OFF_Q     = 1141184;  // float[CAPP*G]
constexpr size_t OFF_RS    = 3238336;  // float[CAPH*G]
constexpr size_t OFF_EMB   = 3762624;  // float[2G] (only [0:256] used)
constexpr size_t OFF_XPROJ = 3764672;  // float[T*4H]

__device__ __forceinline__ float sigmoidf_(float x) { return 1.0f / (1.0f + expf(-x)); }

// Pass 1: degree accumulation + collect edges whose dst == target; flag 1-hop srcs.
__global__ void k_deg_scan(const int* __restrict__ ei, const float* __restrict__ eg,
                           const int* __restrict__ ptgt, float* __restrict__ deg,
                           int* __restrict__ cnt, unsigned char* __restrict__ fH1,
                           int* __restrict__ srcA, float* __restrict__ wA) {
    int target = *ptgt;
    int e = blockIdx.x * 256 + threadIdx.x;
    if (e < E) {
        int d = ei[E + e];
        float w = eg[e];
        atomicAdd(&deg[d], w);
        if (d == target) {
            int s = ei[e];
            int slot = atomicAdd(&cnt[0], 1);
            if (slot < CAPA) { srcA[slot] = s; wA[slot] = w; }
            fH1[s] = 1;
        }
    }
    if (blockIdx.x == 0 && threadIdx.x == 0) fH1[target] = 1;
}

// Pass 2: collect edges whose dst is a needed-h1 node (weights pre-normalized by
// src degree: wB = w * rsqrt(deg[src]+1)); flag srcs as needing p/q.
__global__ void k_scan2(const int* __restrict__ ei, const float* __restrict__ eg,
                        const float* __restrict__ deg,
                        const unsigned char* __restrict__ fH1, unsigned char* __restrict__ fP,
                        int* __restrict__ cnt, int* __restrict__ srcB,
                        int* __restrict__ dstB, float* __restrict__ wB) {
    int e = blockIdx.x * 256 + threadIdx.x;
    if (e >= E) return;
    int d = ei[E + e];
    if (fH1[d]) {
        int s = ei[e];
        float w = eg[e];
        int slot = atomicAdd(&cnt[1], 1);
        if (slot < CAPB) {
            srcB[slot] = s; dstB[slot] = d;
            wB[slot] = w * rsqrtf(deg[s] + 1.0f);
        }
        fP[s] = 1;
    }
}

// Compact flagged node sets into lists with index maps.
__global__ void k_compact(const unsigned char* __restrict__ fH1, const unsigned char* __restrict__ fP,
                          int* __restrict__ cnt, int* __restrict__ listP, int* __restrict__ listH,
                          int* __restrict__ idxP, int* __restrict__ idxH1) {
    int n = blockIdx.x * 256 + threadIdx.x;
    if (n >= N) return;
    if (fH1[n]) {
        int sh = atomicAdd(&cnt[3], 1);
        if (sh < CAPH) listH[sh] = n;
        idxH1[n] = sh;
    }
    if (fP[n] || fH1[n]) {
        int sp = atomicAdd(&cnt[2], 1);
        if (sp < CAPP) listP[sp] = n;
        idxP[n] = sp;
    }
}

// q[row] = relu((x[n]*feat_gate) @ W_proj + b_proj) @ W_g1.
// 256 blocks, round-robin rows (all blocks active), deep unroll.
__global__ void k_pq(const float* __restrict__ x, const float* __restrict__ fgate,
                     const float* __restrict__ Wproj, const float* __restrict__ bproj,
                     const float* __restrict__ Wg1, const int* __restrict__ cnt,
                     const int* __restrict__ listP, float* __restrict__ q) {
    __shared__ float xm[F];
    __shared__ float part[256];
    __shared__ float pv[P];
    int nP = min(cnt[2], CAPP);
    int tid = threadIdx.x;  // 256
    for (int row = blockIdx.x; row < nP; row += 256) {
        int n = listP[row];
        __syncthreads();  // protect LDS reuse across row iterations
        for (int i = tid; i < F; i += 256) xm[i] = x[(size_t)n * F + i] * fgate[i];
        __syncthreads();
        int col = tid & 127, kh = tid >> 7;
        const float* wp = Wproj + (size_t)(kh * 256) * P + col;
        const float* xh = xm + kh * 256;
        float acc = 0.0f;
        #pragma unroll 16
        for (int k = 0; k < 256; k++) acc += xh[k] * wp[(size_t)k * P];
        part[tid] = acc;
        __syncthreads();
        if (tid < P) pv[tid] = fmaxf(part[tid] + part[tid + 128] + bproj[tid], 0.0f);
        __syncthreads();
        float a = 0.0f;
        #pragma unroll 16
        for (int k = 0; k < P; k++) a += pv[k] * Wg1[k * G + tid];
        q[(size_t)row * G + tid] = a;
    }
}

// h1 for 1-hop-set nodes, then r = h1 @ W_g2. Edge list staged through LDS.
// Also capture h1[target] -> emb[0:256].
__global__ void k_h1(const int* __restrict__ ptgt, const float* __restrict__ deg,
                     const int* __restrict__ cnt, const int* __restrict__ listH,
                     const int* __restrict__ idxP, const int* __restrict__ srcB,
                     const int* __restrict__ dstB, const float* __restrict__ wB,
                     const float* __restrict__ q, const float* __restrict__ bg1,
                     const float* __restrict__ Wg2,
                     float* __restrict__ rs, float* __restrict__ emb) {
    __shared__ float h1row[G];
    __shared__ int ldst[512];
    __shared__ int lsrc[512];
    __shared__ float lw[512];
    int b = blockIdx.x;
    int nH = min(cnt[3], CAPH);
    if (b >= nH) return;
    int n = listH[b];
    int target = *ptgt;
    int g = threadIdx.x;  // 256 threads
    float dn = rsqrtf(deg[n] + 1.0f);
    float acc = bg1[g] + q[(size_t)idxP[n] * G + g] * dn * dn;
    int nB = min(cnt[1], CAPB);
    for (int base = 0; base < nB; base += 512) {
        int m = min(512, nB - base);
        __syncthreads();
        for (int i = g; i < m; i += 256) {
            ldst[i] = dstB[base + i]; lsrc[i] = srcB[base + i]; lw[i] = wB[base + i];
        }
        __syncthreads();
        for (int e = 0; e < m; e++) {
            if (ldst[e] == n)
                acc += lw[e] * dn * q[(size_t)idxP[lsrc[e]] * G + g];
        }
    }
    float hv = fmaxf(acc, 0.0f);
    h1row[g] = hv;
    if (n == target) emb[g] = hv;
    __syncthreads();
    float r = 0.0f;
    #pragma unroll 8
    for (int k = 0; k < G; k++) r += h1row[k] * Wg2[k * G + g];
    rs[(size_t)b * G + g] = r;
}

// xproj[t][j] = seq[t] @ W_ih[:,j] + b_ih[j] + b_hh[j]; seq built in-LDS from
// cached + emb (h1 target) + h2 target (recomputed redundantly per block).
// 32 blocks x 256 threads; block owns 32 columns, all T rows.
__global__ void k_xproj(const float* __restrict__ cached, const float* __restrict__ emb,
                        const int* __restrict__ ptgt, const int* __restrict__ pepos,
                        const float* __restrict__ deg, const int* __restrict__ cnt,
                        const int* __restrict__ idxH1, const int* __restrict__ srcA,
                        const float* __restrict__ wA, const float* __restrict__ rs,
                        const float* __restrict__ bg2,
                        const float* __restrict__ Wih, const float* __restrict__ bih,
                        const float* __restrict__ bhh, float* __restrict__ xproj) {
    __shared__ float s[T][2 * G];  // 48 KB
    int tid = threadIdx.x;
    int epos = *pepos;
    for (int i = tid; i < T * 2 * G; i += 256) {
        int t = i >> 9, k = i & 511;
        s[t][k] = (t == epos && k < G) ? emb[k] : cached[i];
    }
    // h2[target] (redundant per block, ~16 edges)
    int target = *ptgt;
    float dt = rsqrtf(deg[target] + 1.0f);
    float h2v = 0.0f;
    if (tid < G) {
        int it = idxH1[target];
        h2v = bg2[tid] + rs[(size_t)it * G + tid] * dt * dt;
        int nA = min(cnt[0], CAPA);
        for (int e = 0; e < nA; e++) {
            int sn = srcA[e];
            h2v += rsqrtf(deg[sn] + 1.0f) * wA[e] * dt * rs[(size_t)idxH1[sn] * G + tid];
        }
    }
    __syncthreads();
    if (tid < G) s[epos][G + tid] = fmaxf(h2v, 0.0f);
    __syncthreads();
    int col = blockIdx.x * 32 + (tid & 31);
    int tg = tid >> 5;  // 0..7
    float base = bih[col] + bhh[col];
    float acc[3];
    #pragma unroll
    for (int i = 0; i < 3; i++) acc[i] = base;
    #pragma unroll 16
    for (int k = 0; k < 2 * G; k++) {
        float wv = Wih[k * 4 * H + col];
        #pragma unroll
        for (int i = 0; i < 3; i++) acc[i] += s[tg + i * 8][k] * wv;
    }
    #pragma unroll
    for (int i = 0; i < 3; i++) xproj[(tg + i * 8) * 4 * H + col] = acc[i];
}

// LSTM over 4 cooperating WGs x 256 threads, all forced onto ONE XCD:
// launch 64 WGs; each reads its physical XCC_ID and takes a ticket on a
// per-XCD counter; the WG taking ticket 3 CASes its XCD as winner (so the
// winner XCD provably has >=4 claimants); tickets 0-3 on the winner XCD
// become roles 0-3, all other WGs exit. Output is role-symmetric ->
// deterministic. Cross-WG h-exchange then uses VOLATILE (sc0) loads/stores
// that stay in the shared per-XCD L2 (~200cy) instead of agent-scope (sc1)
// IF$ round trips (~700ns+) — R6's 3.8us/step was this sc1 latency.
// Thread owns gate column (tid>>6)*H + role*64 + (tid&63); its 256-element
// W_hh column lives in 16 named fv16 register vectors (1 wave/SIMD -> cap 512).
typedef float fv16 __attribute__((ext_vector_type(16)));

#define LDE(J,Eidx) wv##J[Eidx] = Whh[(size_t)((J) * 16 + (Eidx)) * 1024 + col];
#define LDV(J) LDE(J,0) LDE(J,1) LDE(J,2) LDE(J,3) LDE(J,4) LDE(J,5) LDE(J,6) LDE(J,7) \
               LDE(J,8) LDE(J,9) LDE(J,10) LDE(J,11) LDE(J,12) LDE(J,13) LDE(J,14) LDE(J,15)

#define DOT4(J,Q,ACC) { float4 h4 = hb4[(J) * 4 + (Q)]; \
    ACC += h4.x * wv##J[4*(Q)] + h4.y * wv##J[4*(Q)+1] \
         + h4.z * wv##J[4*(Q)+2] + h4.w * wv##J[4*(Q)+3]; }
#define DOTV(J) DOT4(J,0,a0) DOT4(J,1,a1) DOT4(J,2,a2) DOT4(J,3,a3)

__global__ __launch_bounds__(256, 1) void k_lstm(
        const float* __restrict__ Whh, const float* __restrict__ xproj,
        unsigned long long* __restrict__ comm, int* __restrict__ ctrl,
        const float* __restrict__ Watt, const float* __restrict__ batt,
        const float* __restrict__ Wp1, const float* __restrict__ bp1,
        const float* __restrict__ Wp2, const float* __restrict__ bp2,
        float* __restrict__ out) {
    __shared__ __align__(16) float hbuf[H];   // 1 KB
    __shared__ float glds[4 * 64];            // gate exchange
    __shared__ float rnn_lds[T][H];           // 24 KB (role-0 tail)
    __shared__ float sc[T];
    __shared__ float attw[T];
    __shared__ float ctx_l[H];
    __shared__ float watt_l[H];
    __shared__ float part[256];
    __shared__ float hid_l[64];
    __shared__ float wp2_l[64];
    __shared__ int role_s;

    int tid = threadIdx.x;     // 0..255

    // ---- same-XCD role claiming ----
    if (tid == 0) {
        int xcd;
        asm volatile("s_getreg_b32 %0, hwreg(HW_REG_XCC_ID)" : "=s"(xcd));
        xcd &= 7;
        int role = -1;
        int ticket = __hip_atomic_fetch_add(&ctrl[xcd], 1, __ATOMIC_RELAXED,
                                            __HIP_MEMORY_SCOPE_AGENT);
        if (ticket < 4) {
            if (ticket == 3) {  // 4th claimant on this XCD: try to crown it
                int expected = 0;
                __hip_atomic_compare_exchange_strong(&ctrl[8], &expected, xcd + 1,
                        __ATOMIC_RELAXED, __ATOMIC_RELAXED, __HIP_MEMORY_SCOPE_AGENT);
            }
            int wnr;
            do {
                wnr = __hip_atomic_load(&ctrl[8], __ATOMIC_RELAXED, __HIP_MEMORY_SCOPE_AGENT);
                __builtin_amdgcn_s_sleep(1);
            } while (wnr == 0);
            if (wnr == xcd + 1) role = ticket;
        }
        role_s = role;
    }
    __syncthreads();
    int w = role_s;
    if (w < 0) return;
    int l = tid & 63;                       // local channel
    int col = (tid >> 6) * H + w * 64 + l;  // global gate column

    // Preload this thread's W_hh column into 256 register lanes (coalesced).
    fv16 wv0, wv1, wv2, wv3, wv4, wv5, wv6, wv7;
    fv16 wv8, wv9, wv10, wv11, wv12, wv13, wv14, wv15;
    LDV(0) LDV(1) LDV(2) LDV(3) LDV(4) LDV(5) LDV(6) LDV(7)
    LDV(8) LDV(9) LDV(10) LDV(11) LDV(12) LDV(13) LDV(14) LDV(15)

    const float4* hb4 = (const float4*)hbuf;
    hbuf[tid] = 0.0f;
    float cstate = 0.0f;            // live in tid < 64
    float xnext = xproj[col];       // prefetch t=0
    __syncthreads();

    for (int t = 0; t < T; t++) {
        float xt = xnext;
        if (t + 1 < T) xnext = xproj[(t + 1) * 4 * H + col];  // in flight during dot
        float a0 = 0.0f, a1 = 0.0f, a2 = 0.0f, a3 = 0.0f;
        DOTV(0) DOTV(1) DOTV(2) DOTV(3) DOTV(4) DOTV(5) DOTV(6) DOTV(7)
        DOTV(8) DOTV(9) DOTV(10) DOTV(11) DOTV(12) DOTV(13) DOTV(14) DOTV(15)
        glds[tid] = ((a0 + a1) + (a2 + a3)) + xt;
        __syncthreads();
        int s = t + 1;
        if (tid < 64) {
            float gi = glds[l], gf = glds[64 + l], gg = glds[128 + l], go = glds[192 + l];
            cstate = sigmoidf_(gf) * cstate + sigmoidf_(gi) * tanhf(gg);
            float hv = sigmoidf_(go) * tanhf(cstate);
            hbuf[w * 64 + l] = hv;  // own channels direct to LDS
            unsigned long long word =
                ((unsigned long long)__float_as_uint(hv) << 32) | (unsigned)s;
            volatile unsigned long long* cbw = comm + (size_t)(s & 1) * 256;
            cbw[w * 64 + l] = word;  // sc0 store -> shared L2
        }
        // poll foreign channels via L2 (volatile); agent-scope fallback guards
        // against any L1 staleness pathology.
        if ((tid >> 6) != w) {
            volatile const unsigned long long* cb = comm + (size_t)(s & 1) * 256;
            unsigned long long wd = cb[tid];
            int spins = 0;
            while ((unsigned)wd != (unsigned)s) {
                if (++spins > 8192) {
                    wd = __hip_atomic_load(&comm[(size_t)(s & 1) * 256 + tid],
                                           __ATOMIC_RELAXED, __HIP_MEMORY_SCOPE_AGENT);
                    spins = 0;
                } else {
                    wd = cb[tid];
                }
            }
            hbuf[tid] = __uint_as_float((unsigned)(wd >> 32));
        }
        __syncthreads();
        if (w == 0) rnn_lds[t][tid] = hbuf[tid];
    }

    if (w != 0) return;
    // ---- attention + MLP tail (role 0 only) ----
    watt_l[tid] = Watt[tid];
    if (tid < 64) wp2_l[tid] = Wp2[tid];
    __syncthreads();
    if (tid < T) {
        float sv = 0.0f;
        #pragma unroll 8
        for (int h = 0; h < H; h++) sv += rnn_lds[tid][h] * watt_l[h];
        sc[tid] = tanhf(sv + batt[0]);
    }
    __syncthreads();
    if (tid == 0) {
        float m = -1e30f;
        for (int t = 0; t < T; t++) m = fmaxf(m, sc[t]);
        float su = 0.0f;
        for (int t = 0; t < T; t++) { float e = expf(sc[t] - m); attw[t] = e; su += e; }
        float inv = 1.0f / su;
        for (int t = 0; t < T; t++) attw[t] *= inv;
    }
    __syncthreads();
    {
        float a = 0.0f;
        #pragma unroll
        for (int t = 0; t < T; t++) a += rnn_lds[t][tid] * attw[t];
        ctx_l[tid] = a;
    }
    __syncthreads();
    {
        int col2 = tid & 63, sl = tid >> 6;  // 4 k-slices of 64
        float a = 0.0f;
        #pragma unroll 16
        for (int kk = 0; kk < 64; kk++) {
            int k = sl * 64 + kk;
            a += ctx_l[k] * Wp1[k * 64 + col2];
        }
        part[tid] = a;
    }
    __syncthreads();
    if (tid < 64) {
        float a = bp1[tid] + part[tid] + part[64 + tid] + part[128 + tid] + part[192 + tid];
        hid_l[tid] = fmaxf(a, 0.0f);
    }
    __syncthreads();
    if (tid == 0) {
        float r = bp2[0];
        #pragma unroll
        for (int j = 0; j < 64; j++) r += hid_l[j] * wp2_l[j];
        out[0] = (r > 20.0f) ? r : log1pf(expf(r));
    }
}

extern "C" void kernel_launch(void* const* d_in, const int* in_sizes, int n_in,
                              void* d_out, int out_size, void* d_ws, size_t ws_size,
                              hipStream_t stream) {
    const float* x      = (const float*)d_in[0];
    const int*   ei     = (const int*)d_in[1];
    const float* fgate  = (const float*)d_in[2];
    const float* egate  = (const float*)d_in[3];
    const float* cached = (const float*)d_in[4];
    const float* Wproj  = (const float*)d_in[5];
    const float* bproj  = (const float*)d_in[6];
    const float* Wg1    = (const float*)d_in[7];
    const float* bg1    = (const float*)d_in[8];
    const float* Wg2    = (const float*)d_in[9];
    const float* bg2    = (const float*)d_in[10];
    const float* Wih    = (const float*)d_in[11];
    const float* Whh    = (const float*)d_in[12];
    const float* bih    = (const float*)d_in[13];
    const float* bhh    = (const float*)d_in[14];
    const float* Watt   = (const float*)d_in[15];
    const float* batt   = (const float*)d_in[16];
    const float* Wp1    = (const float*)d_in[17];
    const float* bp1    = (const float*)d_in[18];
    const float* Wp2    = (const float*)d_in[19];
    const float* bp2    = (const float*)d_in[20];
    const int*   ptgt   = (const int*)d_in[21];
    const int*   pepos  = (const int*)d_in[22];

    char* ws = (char*)d_ws;
    float* deg   = (float*)(ws + OFF_DEG);
    int*   cnt   = (int*)(ws + OFF_CNT);
    unsigned long long* comm = (unsigned long long*)(ws + OFF_COMM);
    unsigned char* fH1 = (unsigned char*)(ws + OFF_FH1);
    unsigned char* fP  = (unsigned char*)(ws + OFF_FP);
    int*   idxP  = (int*)(ws + OFF_IDXP);
    int*   idxH1 = (int*)(ws + OFF_IDXH1);
    int*   srcA  = (int*)(ws + OFF_SRCA);
    float* wA    = (float*)(ws + OFF_WA);
    int*   srcB  = (int*)(ws + OFF_SRCB);
    int*   dstB  = (int*)(ws + OFF_DSTB);
    float* wB    = (float*)(ws + OFF_WB);
    int*   listP = (int*)(ws + OFF_LISTP);
    int*   listH = (int*)(ws + OFF_LISTH);
    float* q     = (float*)(ws + OFF_Q);
    float* rs    = (float*)(ws + OFF_RS);
    float* emb   = (float*)(ws + OFF_EMB);
    float* xproj = (float*)(ws + OFF_XPROJ);

    hipMemsetAsync(ws, 0, ZERO_END, stream);

    k_deg_scan<<<(E + 255) / 256, 256, 0, stream>>>(ei, egate, ptgt, deg, cnt, fH1, srcA, wA);
    k_scan2<<<(E + 255) / 256, 256, 0, stream>>>(ei, egate, deg, fH1, fP, cnt, srcB, dstB, wB);
    k_compact<<<(N + 255) / 256, 256, 0, stream>>>(fH1, fP, cnt, listP, listH, idxP, idxH1);
    k_pq<<<256, 256, 0, stream>>>(x, fgate, Wproj, bproj, Wg1, cnt, listP, q);
    k_h1<<<CAPH, 256, 0, stream>>>(ptgt, deg, cnt, listH, idxP, srcB, dstB, wB, q, bg1, Wg2, rs, emb);
    k_xproj<<<32, 256, 0, stream>>>(cached, emb, ptgt, pepos, deg, cnt, idxH1, srcA, wA, rs, bg2,
                                    Wih, bih, bhh, xproj);
    k_lstm<<<64, 256, 0, stream>>>(Whh, xproj, comm, cnt + 4, Watt, batt, Wp1, bp1, Wp2, bp2,
                                   (float*)d_out);
}

// Round 8
// 195.673 us; speedup vs baseline: 3.4968x; 1.0325x over previous
//
#include <hip/hip_runtime.h>
#include <math.h>

// Problem constants (from reference)
constexpr int N = 50000, E = 800000, F = 512, P = 128, G = 256, H = 256, T = 24;
// Capacity caps (expected: ~16 edges->target, ~290 2-hop edges, ~300 nodes)
constexpr int CAPA = 4096, CAPB = 32768, CAPP = 2048, CAPH = 512;

// Workspace layout (bytes), 64-aligned
constexpr size_t OFF_DEG   = 0;        // float[N]
constexpr size_t OFF_CNT   = 200704;   // int[16]: 0=cntA,1=cntB,2=cntP,3=cntH,4..11=xcd tickets,12=winner
constexpr size_t OFF_COMM  = 200768;   // ull[2][256] tagged h-words (ping-pong)
constexpr size_t OFF_FH1   = 204864;   // uchar[N]
constexpr size_t OFF_FP    = 254912;   // uchar[N]
constexpr size_t ZERO_END  = 304960;   // memset [0, ZERO_END)
constexpr size_t OFF_IDXP  = 304960;   // int[N]
constexpr size_t OFF_IDXH1 = 504960;   // int[N]
constexpr size_t OFF_SRCA  = 704960;   // int[CAPA]
constexpr size_t OFF_WA    = 721344;   // float[CAPA]
constexpr size_t OFF_SRCB  = 737728;   // int[CAPB]
constexpr size_t OFF_DSTB  = 868800;   // int[CAPB]
constexpr size_t OFF_WB    = 999872;   // float[CAPB] (pre-normalized by src degree)
constexpr size_t OFF_LISTP = 1130944;  // int[CAPP]
constexpr size_t OFF_LISTH = 1139136;  // int[CAPH]
constexpr size_t OFF_Q     = 1141184;  // float[CAPP*G]
constexpr size_t OFF_RS    = 3238336;  // float[CAPH*G]
constexpr size_t OFF_EMB   = 3762624;  // float[2G] (only [0:256] used)
constexpr size_t OFF_XPROJ = 3764672;  // float[T*4H]

__device__ __forceinline__ float sigmoidf_(float x) { return 1.0f / (1.0f + expf(-x)); }
// Fast forms via v_exp_f32 + v_rcp_f32 (~2 ulp, fine vs 1.4e-2 threshold)
__device__ __forceinline__ float fsig_(float x) {
    return __builtin_amdgcn_rcpf(1.0f + __expf(-x));
}
__device__ __forceinline__ float ftanh_(float x) {
    return 1.0f - 2.0f * __builtin_amdgcn_rcpf(1.0f + __expf(2.0f * x));
}

// Pass 1: degree accumulation + collect edges whose dst == target; flag 1-hop srcs.
__global__ void k_deg_scan(const int* __restrict__ ei, const float* __restrict__ eg,
                           const int* __restrict__ ptgt, float* __restrict__ deg,
                           int* __restrict__ cnt, unsigned char* __restrict__ fH1,
                           int* __restrict__ srcA, float* __restrict__ wA) {
    int target = *ptgt;
    int e = blockIdx.x * 256 + threadIdx.x;
    if (e < E) {
        int d = ei[E + e];
        float w = eg[e];
        atomicAdd(&deg[d], w);
        if (d == target) {
            int s = ei[e];
            int slot = atomicAdd(&cnt[0], 1);
            if (slot < CAPA) { srcA[slot] = s; wA[slot] = w; }
            fH1[s] = 1;
        }
    }
    if (blockIdx.x == 0 && threadIdx.x == 0) fH1[target] = 1;
}

// Pass 2: collect edges whose dst is a needed-h1 node (weights pre-normalized by
// src degree: wB = w * rsqrt(deg[src]+1)); flag srcs as needing p/q.
__global__ void k_scan2(const int* __restrict__ ei, const float* __restrict__ eg,
                        const float* __restrict__ deg,
                        const unsigned char* __restrict__ fH1, unsigned char* __restrict__ fP,
                        int* __restrict__ cnt, int* __restrict__ srcB,
                        int* __restrict__ dstB, float* __restrict__ wB) {
    int e = blockIdx.x * 256 + threadIdx.x;
    if (e >= E) return;
    int d = ei[E + e];
    if (fH1[d]) {
        int s = ei[e];
        float w = eg[e];
        int slot = atomicAdd(&cnt[1], 1);
        if (slot < CAPB) {
            srcB[slot] = s; dstB[slot] = d;
            wB[slot] = w * rsqrtf(deg[s] + 1.0f);
        }
        fP[s] = 1;
    }
}

// Compact flagged node sets into lists with index maps.
__global__ void k_compact(const unsigned char* __restrict__ fH1, const unsigned char* __restrict__ fP,
                          int* __restrict__ cnt, int* __restrict__ listP, int* __restrict__ listH,
                          int* __restrict__ idxP, int* __restrict__ idxH1) {
    int n = blockIdx.x * 256 + threadIdx.x;
    if (n >= N) return;
    if (fH1[n]) {
        int sh = atomicAdd(&cnt[3], 1);
        if (sh < CAPH) listH[sh] = n;
        idxH1[n] = sh;
    }
    if (fP[n] || fH1[n]) {
        int sp = atomicAdd(&cnt[2], 1);
        if (sp < CAPP) listP[sp] = n;
        idxP[n] = sp;
    }
}

// q[row] = relu((x[n]*feat_gate) @ W_proj + b_proj) @ W_g1.
// 256 blocks, round-robin rows (all blocks active), deep unroll.
__global__ void k_pq(const float* __restrict__ x, const float* __restrict__ fgate,
                     const float* __restrict__ Wproj, const float* __restrict__ bproj,
                     const float* __restrict__ Wg1, const int* __restrict__ cnt,
                     const int* __restrict__ listP, float* __restrict__ q) {
    __shared__ float xm[F];
    __shared__ float part[256];
    __shared__ float pv[P];
    int nP = min(cnt[2], CAPP);
    int tid = threadIdx.x;  // 256
    for (int row = blockIdx.x; row < nP; row += 256) {
        int n = listP[row];
        __syncthreads();  // protect LDS reuse across row iterations
        for (int i = tid; i < F; i += 256) xm[i] = x[(size_t)n * F + i] * fgate[i];
        __syncthreads();
        int col = tid & 127, kh = tid >> 7;
        const float* wp = Wproj + (size_t)(kh * 256) * P + col;
        const float* xh = xm + kh * 256;
        float acc = 0.0f;
        #pragma unroll 16
        for (int k = 0; k < 256; k++) acc += xh[k] * wp[(size_t)k * P];
        part[tid] = acc;
        __syncthreads();
        if (tid < P) pv[tid] = fmaxf(part[tid] + part[tid + 128] + bproj[tid], 0.0f);
        __syncthreads();
        float a = 0.0f;
        #pragma unroll 16
        for (int k = 0; k < P; k++) a += pv[k] * Wg1[k * G + tid];
        q[(size_t)row * G + tid] = a;
    }
}

// h1 for 1-hop-set nodes, then r = h1 @ W_g2. Edge list staged through LDS.
// Also capture h1[target] -> emb[0:256].
__global__ void k_h1(const int* __restrict__ ptgt, const float* __restrict__ deg,
                     const int* __restrict__ cnt, const int* __restrict__ listH,
                     const int* __restrict__ idxP, const int* __restrict__ srcB,
                     const int* __restrict__ dstB, const float* __restrict__ wB,
                     const float* __restrict__ q, const float* __restrict__ bg1,
                     const float* __restrict__ Wg2,
                     float* __restrict__ rs, float* __restrict__ emb) {
    __shared__ float h1row[G];
    __shared__ int ldst[512];
    __shared__ int lsrc[512];
    __shared__ float lw[512];
    int b = blockIdx.x;
    int nH = min(cnt[3], CAPH);
    if (b >= nH) return;
    int n = listH[b];
    int target = *ptgt;
    int g = threadIdx.x;  // 256 threads
    float dn = rsqrtf(deg[n] + 1.0f);
    float acc = bg1[g] + q[(size_t)idxP[n] * G + g] * dn * dn;
    int nB = min(cnt[1], CAPB);
    for (int base = 0; base < nB; base += 512) {
        int m = min(512, nB - base);
        __syncthreads();
        for (int i = g; i < m; i += 256) {
            ldst[i] = dstB[base + i]; lsrc[i] = srcB[base + i]; lw[i] = wB[base + i];
        }
        __syncthreads();
        for (int e = 0; e < m; e++) {
            if (ldst[e] == n)
                acc += lw[e] * dn * q[(size_t)idxP[lsrc[e]] * G + g];
        }
    }
    float hv = fmaxf(acc, 0.0f);
    h1row[g] = hv;
    if (n == target) emb[g] = hv;
    __syncthreads();
    float r = 0.0f;
    #pragma unroll 8
    for (int k = 0; k < G; k++) r += h1row[k] * Wg2[k * G + g];
    rs[(size_t)b * G + g] = r;
}

// xproj[t][j] = seq[t] @ W_ih[:,j] + b_ih[j] + b_hh[j]; seq built in-LDS from
// cached + emb (h1 target) + h2 target (recomputed redundantly per block).
// 32 blocks x 256 threads; block owns 32 columns, all T rows.
__global__ void k_xproj(const float* __restrict__ cached, const float* __restrict__ emb,
                        const int* __restrict__ ptgt, const int* __restrict__ pepos,
                        const float* __restrict__ deg, const int* __restrict__ cnt,
                        const int* __restrict__ idxH1, const int* __restrict__ srcA,
                        const float* __restrict__ wA, const float* __restrict__ rs,
                        const float* __restrict__ bg2,
                        const float* __restrict__ Wih, const float* __restrict__ bih,
                        const float* __restrict__ bhh, float* __restrict__ xproj) {
    __shared__ float s[T][2 * G];  // 48 KB
    int tid = threadIdx.x;
    int epos = *pepos;
    for (int i = tid; i < T * 2 * G; i += 256) {
        int t = i >> 9, k = i & 511;
        s[t][k] = (t == epos && k < G) ? emb[k] : cached[i];
    }
    // h2[target] (redundant per block, ~16 edges)
    int target = *ptgt;
    float dt = rsqrtf(deg[target] + 1.0f);
    float h2v = 0.0f;
    if (tid < G) {
        int it = idxH1[target];
        h2v = bg2[tid] + rs[(size_t)it * G + tid] * dt * dt;
        int nA = min(cnt[0], CAPA);
        for (int e = 0; e < nA; e++) {
            int sn = srcA[e];
            h2v += rsqrtf(deg[sn] + 1.0f) * wA[e] * dt * rs[(size_t)idxH1[sn] * G + tid];
        }
    }
    __syncthreads();
    if (tid < G) s[epos][G + tid] = fmaxf(h2v, 0.0f);
    __syncthreads();
    int col = blockIdx.x * 32 + (tid & 31);
    int tg = tid >> 5;  // 0..7
    float base = bih[col] + bhh[col];
    float acc[3];
    #pragma unroll
    for (int i = 0; i < 3; i++) acc[i] = base;
    #pragma unroll 16
    for (int k = 0; k < 2 * G; k++) {
        float wv = Wih[k * 4 * H + col];
        #pragma unroll
        for (int i = 0; i < 3; i++) acc[i] += s[tg + i * 8][k] * wv;
    }
    #pragma unroll
    for (int i = 0; i < 3; i++) xproj[(tg + i * 8) * 4 * H + col] = acc[i];
}

// LSTM over 4 cooperating WGs x 256 threads on ONE XCD (ticket/crown claim, R7).
// Thread owns gate column (tid>>6)*H + role*64 + (tid&63); its 256-element W_hh
// column lives in 16 named fv16 register vectors.
// R8 change: poll discipline. R3/R6/R7 all hit the same ~3.5us/step floor
// regardless of scope/mechanism -> the floor is SELF-INFLICTED L2 queue
// congestion from back-to-back spin loads (12 waves hammering 32 cachelines),
// not coherence latency. Fix: exactly ONE thread polls each foreign word
// (192 pollers x 1 word) with s_sleep(1) backoff between attempts, so the L2
// stays idle and the publisher's store lands immediately.
typedef float fv16 __attribute__((ext_vector_type(16)));

#define LDE(J,Eidx) wv##J[Eidx] = Whh[(size_t)((J) * 16 + (Eidx)) * 1024 + col];
#define LDV(J) LDE(J,0) LDE(J,1) LDE(J,2) LDE(J,3) LDE(J,4) LDE(J,5) LDE(J,6) LDE(J,7) \
               LDE(J,8) LDE(J,9) LDE(J,10) LDE(J,11) LDE(J,12) LDE(J,13) LDE(J,14) LDE(J,15)

#define DOT4(J,Q,ACC) { float4 h4 = hb4[(J) * 4 + (Q)]; \
    ACC += h4.x * wv##J[4*(Q)] + h4.y * wv##J[4*(Q)+1] \
         + h4.z * wv##J[4*(Q)+2] + h4.w * wv##J[4*(Q)+3]; }
#define DOTV(J) DOT4(J,0,a0) DOT4(J,1,a1) DOT4(J,2,a2) DOT4(J,3,a3)

__global__ __launch_bounds__(256, 1) void k_lstm(
        const float* __restrict__ Whh, const float* __restrict__ xproj,
        unsigned long long* __restrict__ comm, int* __restrict__ ctrl,
        const float* __restrict__ Watt, const float* __restrict__ batt,
        const float* __restrict__ Wp1, const float* __restrict__ bp1,
        const float* __restrict__ Wp2, const float* __restrict__ bp2,
        float* __restrict__ out) {
    __shared__ __align__(16) float hbuf[H];   // 1 KB
    __shared__ float glds[4 * 64];            // gate exchange
    __shared__ float rnn_lds[T][H];           // 24 KB (role-0 tail)
    __shared__ float sc[T];
    __shared__ float attw[T];
    __shared__ float ctx_l[H];
    __shared__ float watt_l[H];
    __shared__ float part[256];
    __shared__ float hid_l[64];
    __shared__ float wp2_l[64];
    __shared__ int role_s;

    int tid = threadIdx.x;     // 0..255

    // ---- same-XCD role claiming ----
    if (tid == 0) {
        int xcd;
        asm volatile("s_getreg_b32 %0, hwreg(HW_REG_XCC_ID)" : "=s"(xcd));
        xcd &= 7;
        int role = -1;
        int ticket = __hip_atomic_fetch_add(&ctrl[xcd], 1, __ATOMIC_RELAXED,
                                            __HIP_MEMORY_SCOPE_AGENT);
        if (ticket < 4) {
            if (ticket == 3) {  // 4th claimant on this XCD: try to crown it
                int expected = 0;
                __hip_atomic_compare_exchange_strong(&ctrl[8], &expected, xcd + 1,
                        __ATOMIC_RELAXED, __ATOMIC_RELAXED, __HIP_MEMORY_SCOPE_AGENT);
            }
            int wnr;
            do {
                wnr = __hip_atomic_load(&ctrl[8], __ATOMIC_RELAXED, __HIP_MEMORY_SCOPE_AGENT);
                __builtin_amdgcn_s_sleep(1);
            } while (wnr == 0);
            if (wnr == xcd + 1) role = ticket;
        }
        role_s = role;
    }
    __syncthreads();
    int w = role_s;
    if (w < 0) return;
    int l = tid & 63;                       // local channel
    int col = (tid >> 6) * H + w * 64 + l;  // global gate column

    // Preload this thread's W_hh column into 256 register lanes (coalesced).
    fv16 wv0, wv1, wv2, wv3, wv4, wv5, wv6, wv7;
    fv16 wv8, wv9, wv10, wv11, wv12, wv13, wv14, wv15;
    LDV(0) LDV(1) LDV(2) LDV(3) LDV(4) LDV(5) LDV(6) LDV(7)
    LDV(8) LDV(9) LDV(10) LDV(11) LDV(12) LDV(13) LDV(14) LDV(15)

    // This thread's poll assignment: one foreign word (tid<192).
    int pch = tid + (tid >= w * 64 ? 64 : 0);

    const float4* hb4 = (const float4*)hbuf;
    hbuf[tid] = 0.0f;
    float cstate = 0.0f;            // live in tid < 64
    float xnext = xproj[col];       // prefetch t=0
    __syncthreads();

    for (int t = 0; t < T; t++) {
        float xt = xnext;
        if (t + 1 < T) xnext = xproj[(t + 1) * 4 * H + col];  // in flight during dot
        float a0 = 0.0f, a1 = 0.0f, a2 = 0.0f, a3 = 0.0f;
        DOTV(0) DOTV(1) DOTV(2) DOTV(3) DOTV(4) DOTV(5) DOTV(6) DOTV(7)
        DOTV(8) DOTV(9) DOTV(10) DOTV(11) DOTV(12) DOTV(13) DOTV(14) DOTV(15)
        glds[tid] = ((a0 + a1) + (a2 + a3)) + xt;
        __syncthreads();
        int s = t + 1;
        // publishers: compute own 64 channels, store to comm FIRST (in flight),
        // then local LDS writes.
        if (tid < 64) {
            float gi = glds[l], gf = glds[64 + l], gg = glds[128 + l], go = glds[192 + l];
            cstate = fsig_(gf) * cstate + fsig_(gi) * ftanh_(gg);
            float hv = fsig_(go) * ftanh_(cstate);
            unsigned long long word =
                ((unsigned long long)__float_as_uint(hv) << 32) | (unsigned)s;
            volatile unsigned long long* cbw = comm + (size_t)(s & 1) * 256;
            cbw[w * 64 + l] = word;  // sc0 store -> shared L2
            hbuf[w * 64 + l] = hv;   // own channels direct to LDS
        }
        // pollers: one thread per foreign word, s_sleep backoff (keeps L2 idle)
        if (tid < 192) {
            volatile const unsigned long long* cb = comm + (size_t)(s & 1) * 256;
            unsigned long long wd = cb[pch];
            while ((unsigned)wd != (unsigned)s) {
                __builtin_amdgcn_s_sleep(1);
                wd = cb[pch];
            }
            hbuf[pch] = __uint_as_float((unsigned)(wd >> 32));
        }
        __syncthreads();
        if (w == 0) rnn_lds[t][tid] = hbuf[tid];
    }

    if (w != 0) return;
    // ---- attention + MLP tail (role 0 only) ----
    watt_l[tid] = Watt[tid];
    if (tid < 64) wp2_l[tid] = Wp2[tid];
    __syncthreads();
    if (tid < T) {
        float sv = 0.0f;
        #pragma unroll 8
        for (int h = 0; h < H; h++) sv += rnn_lds[tid][h] * watt_l[h];
        sc[tid] = tanhf(sv + batt[0]);
    }
    __syncthreads();
    if (tid == 0) {
        float m = -1e30f;
        for (int t = 0; t < T; t++) m = fmaxf(m, sc[t]);
        float su = 0.0f;
        for (int t = 0; t < T; t++) { float e = expf(sc[t] - m); attw[t] = e; su += e; }
        float inv = 1.0f / su;
        for (int t = 0; t < T; t++) attw[t] *= inv;
    }
    __syncthreads();
    {
        float a = 0.0f;
        #pragma unroll
        for (int t = 0; t < T; t++) a += rnn_lds[t][tid] * attw[t];
        ctx_l[tid] = a;
    }
    __syncthreads();
    {
        int col2 = tid & 63, sl = tid >> 6;  // 4 k-slices of 64
        float a = 0.0f;
        #pragma unroll 16
        for (int kk = 0; kk < 64; kk++) {
            int k = sl * 64 + kk;
            a += ctx_l[k] * Wp1[k * 64 + col2];
        }
        part[tid] = a;
    }
    __syncthreads();
    if (tid < 64) {
        float a = bp1[tid] + part[tid] + part[64 + tid] + part[128 + tid] + part[192 + tid];
        hid_l[tid] = fmaxf(a, 0.0f);
    }
    __syncthreads();
    if (tid == 0) {
        float r = bp2[0];
        #pragma unroll
        for (int j = 0; j < 64; j++) r += hid_l[j] * wp2_l[j];
        out[0] = (r > 20.0f) ? r : log1pf(expf(r));
    }
}

extern "C" void kernel_launch(void* const* d_in, const int* in_sizes, int n_in,
                              void* d_out, int out_size, void* d_ws, size_t ws_size,
                              hipStream_t stream) {
    const float* x      = (const float*)d_in[0];
    const int*   ei     = (const int*)d_in[1];
    const float* fgate  = (const float*)d_in[2];
    const float* egate  = (const float*)d_in[3];
    const float* cached = (const float*)d_in[4];
    const float* Wproj  = (const float*)d_in[5];
    const float* bproj  = (const float*)d_in[6];
    const float* Wg1    = (const float*)d_in[7];
    const float* bg1    = (const float*)d_in[8];
    const float* Wg2    = (const float*)d_in[9];
    const float* bg2    = (const float*)d_in[10];
    const float* Wih    = (const float*)d_in[11];
    const float* Whh    = (const float*)d_in[12];
    const float* bih    = (const float*)d_in[13];
    const float* bhh    = (const float*)d_in[14];
    const float* Watt   = (const float*)d_in[15];
    const float* batt   = (const float*)d_in[16];
    const float* Wp1    = (const float*)d_in[17];
    const float* bp1    = (const float*)d_in[18];
    const float* Wp2    = (const float*)d_in[19];
    const float* bp2    = (const float*)d_in[20];
    const int*   ptgt   = (const int*)d_in[21];
    const int*   pepos  = (const int*)d_in[22];

    char* ws = (char*)d_ws;
    float* deg   = (float*)(ws + OFF_DEG);
    int*   cnt   = (int*)(ws + OFF_CNT);
    unsigned long long* comm = (unsigned long long*)(ws + OFF_COMM);
    unsigned char* fH1 = (unsigned char*)(ws + OFF_FH1);
    unsigned char* fP  = (unsigned char*)(ws + OFF_FP);
    int*   idxP  = (int*)(ws + OFF_IDXP);
    int*   idxH1 = (int*)(ws + OFF_IDXH1);
    int*   srcA  = (int*)(ws + OFF_SRCA);
    float* wA    = (float*)(ws + OFF_WA);
    int*   srcB  = (int*)(ws + OFF_SRCB);
    int*   dstB  = (int*)(ws + OFF_DSTB);
    float* wB    = (float*)(ws + OFF_WB);
    int*   listP = (int*)(ws + OFF_LISTP);
    int*   listH = (int*)(ws + OFF_LISTH);
    float* q     = (float*)(ws + OFF_Q);
    float* rs    = (float*)(ws + OFF_RS);
    float* emb   = (float*)(ws + OFF_EMB);
    float* xproj = (float*)(ws + OFF_XPROJ);

    hipMemsetAsync(ws, 0, ZERO_END, stream);

    k_deg_scan<<<(E + 255) / 256, 256, 0, stream>>>(ei, egate, ptgt, deg, cnt, fH1, srcA, wA);
    k_scan2<<<(E + 255) / 256, 256, 0, stream>>>(ei, egate, deg, fH1, fP, cnt, srcB, dstB, wB);
    k_compact<<<(N + 255) / 256, 256, 0, stream>>>(fH1, fP, cnt, listP, listH, idxP, idxH1);
    k_pq<<<256, 256, 0, stream>>>(x, fgate, Wproj, bproj, Wg1, cnt, listP, q);
    k_h1<<<CAPH, 256, 0, stream>>>(ptgt, deg, cnt, listH, idxP, srcB, dstB, wB, q, bg1, Wg2, rs, emb);
    k_xproj<<<32, 256, 0, stream>>>(cached, emb, ptgt, pepos, deg, cnt, idxH1, srcA, wA, rs, bg2,
                                    Wih, bih, bhh, xproj);
    k_lstm<<<64, 256, 0, stream>>>(Whh, xproj, comm, cnt + 4, Watt, batt, Wp1, bp1, Wp2, bp2,
                                   (float*)d_out);
}